// Round 4
// baseline (1857.770 us; speedup 1.0000x reference)
//
#include <hip/hip_runtime.h>

#define HID 256
#define TLEN 1024
#define BATCH 128

typedef _Float16 half2_t __attribute__((ext_vector_type(2)));

__device__ __forceinline__ float fexp2(float x) { return __builtin_amdgcn_exp2f(x); }
__device__ __forceinline__ float frcp(float x)  { return __builtin_amdgcn_rcpf(x); }
__device__ __forceinline__ float fast_sigmoid(float x) {
  return frcp(1.0f + fexp2(-1.442695040888963f * x));
}
__device__ __forceinline__ float fast_tanh(float x) {
  float e = fexp2(2.885390081777927f * x);
  return 1.0f - 2.0f * frcp(e + 1.0f);
}

__device__ __forceinline__ float dot2acc(half2_t a, half2_t b, float c) {
  return __builtin_amdgcn_fdot2(a, b, c, false);   // v_dot2_f32_f16
}

// One block per batch element, 1024 threads (16 waves, 4 waves/SIMD).
// The allocator clamps at 128 VGPRs for this occupancy (rounds 1-3: both
// launch_bounds(512,1) and waves_per_eu(2,2) failed to raise it; spill
// traffic showed in WRITE_SIZE). So we DESIGN for 128: thread (d=tid>>2,
// q=tid&3) owns the k-quarter q (interleaved 16-B blocks) of W_hh rows
// {d, 256+d, 512+d} = 3*32 = 96 half2 VGPRs + ~30 temps.
// Quarter partials combine via shfl_xor(1),shfl_xor(2); gate math runs
// redundantly on all 4 lanes of a d-group (no divergence).
// hWb (h . Wb_h) uses a 3-slot rotating LDS accumulator with ds_add_f32:
// iter t reads slot r, atomically adds h_new.Wb_h into slot (r+1)%3, and
// tid0 clears slot (r+2)%3 (last read at t-1 pre-barrier, next written at
// t+1 post-barrier -> race-free with ONE barrier per step).
__global__ __launch_bounds__(1024, 1)
void momgru_persistent(const float* __restrict__ x,
                       const float* __restrict__ W_ih,
                       const float* __restrict__ W_hh,
                       const float* __restrict__ b_ih,
                       const float* __restrict__ b_hh,
                       const float* __restrict__ Wb_x,
                       const float* __restrict__ Wb_h,
                       const float* __restrict__ b_beta,
                       const float* __restrict__ s_ptr,
                       const float* __restrict__ W_head,
                       const float* __restrict__ b_head,
                       float* __restrict__ out)  // [0,128) head, [128,128+B*T) betas
{
  const int b    = blockIdx.x;
  const int tid  = threadIdx.x;
  const int lane = tid & 63;
  const int d    = tid >> 2;     // hidden dim 0..255
  const int q    = tid & 3;      // k-quarter selector

  __shared__ half2_t x_sh2[TLEN];         // 4 KB: x packed f16 (x0,x1) per t
  __shared__ half2_t hbuf[2][HID / 2];    // 1 KB, double-buffered f16 h
  __shared__ float   hWb_sh[3];           // rotating h.Wb_h accumulator
  __shared__ float   head_sh;

  // ---- stage x as packed f16 (coalesced reads) ----
  const float* xb = x + (size_t)b * TLEN * 2;
  {
    const int t0 = tid;  // 1024 threads, 1024 timesteps
    float2 xv = reinterpret_cast<const float2*>(xb)[t0];
    x_sh2[t0] = half2_t{(_Float16)xv.x, (_Float16)xv.y};
  }

  // ---- load this thread's weight slice: 8 interleaved 16-B blocks/gate ----
  // f16 block jb = 4*i + q  (i=0..7) covers f32 float4 indices 2*jb, 2*jb+1.
  half2_t wr[32], wz[32], wn[32];
  {
    const float4* rowr = reinterpret_cast<const float4*>(W_hh + (size_t)(0 * HID + d) * HID);
    const float4* rowz = reinterpret_cast<const float4*>(W_hh + (size_t)(1 * HID + d) * HID);
    const float4* rown = reinterpret_cast<const float4*>(W_hh + (size_t)(2 * HID + d) * HID);
#pragma unroll
    for (int i = 0; i < 8; ++i) {
      const int jb = 4 * i + q;
      float4 f0 = rowr[2 * jb];
      float4 f1 = rowr[2 * jb + 1];
      wr[4 * i + 0] = half2_t{(_Float16)f0.x, (_Float16)f0.y};
      wr[4 * i + 1] = half2_t{(_Float16)f0.z, (_Float16)f0.w};
      wr[4 * i + 2] = half2_t{(_Float16)f1.x, (_Float16)f1.y};
      wr[4 * i + 3] = half2_t{(_Float16)f1.z, (_Float16)f1.w};
    }
#pragma unroll
    for (int i = 0; i < 8; ++i) {
      const int jb = 4 * i + q;
      float4 f0 = rowz[2 * jb];
      float4 f1 = rowz[2 * jb + 1];
      wz[4 * i + 0] = half2_t{(_Float16)f0.x, (_Float16)f0.y};
      wz[4 * i + 1] = half2_t{(_Float16)f0.z, (_Float16)f0.w};
      wz[4 * i + 2] = half2_t{(_Float16)f1.x, (_Float16)f1.y};
      wz[4 * i + 3] = half2_t{(_Float16)f1.z, (_Float16)f1.w};
    }
#pragma unroll
    for (int i = 0; i < 8; ++i) {
      const int jb = 4 * i + q;
      float4 f0 = rown[2 * jb];
      float4 f1 = rown[2 * jb + 1];
      wn[4 * i + 0] = half2_t{(_Float16)f0.x, (_Float16)f0.y};
      wn[4 * i + 1] = half2_t{(_Float16)f0.z, (_Float16)f0.w};
      wn[4 * i + 2] = half2_t{(_Float16)f1.x, (_Float16)f1.y};
      wn[4 * i + 3] = half2_t{(_Float16)f1.z, (_Float16)f1.w};
    }
  }

  // ---- per-thread constants (f16-packed where safe) ----
  const half2_t wih_r = half2_t{(_Float16)W_ih[2 * d],             (_Float16)W_ih[2 * d + 1]};
  const half2_t wih_z = half2_t{(_Float16)W_ih[2 * (HID + d)],     (_Float16)W_ih[2 * (HID + d) + 1]};
  const half2_t wih_n = half2_t{(_Float16)W_ih[2 * (2 * HID + d)], (_Float16)W_ih[2 * (2 * HID + d) + 1]};
  const float bih_r = b_ih[d], bih_z = b_ih[HID + d], bih_n = b_ih[2 * HID + d];
  const float bhh_r = b_hh[d], bhh_z = b_hh[HID + d], bhh_n = b_hh[2 * HID + d];
  const half2_t wbx2 = half2_t{(_Float16)Wb_x[0], (_Float16)Wb_x[1]};
  const float bbeta = b_beta[0], sv = s_ptr[0];
  const float wbh_t = Wb_h[d];

  // ---- init state ----
  if (tid < HID / 2) {
    hbuf[0][tid] = half2_t{(_Float16)0.0f, (_Float16)0.0f};
    hbuf[1][tid] = half2_t{(_Float16)0.0f, (_Float16)0.0f};
  }
  if (tid < 3) hWb_sh[tid] = 0.0f;
  if (tid == 3) head_sh = 0.0f;
  float h_old = 0.0f, vr = 0.0f, vz = 0.0f, vn = 0.0f;
  float* betas = out + BATCH;
  __syncthreads();

  int cur = 0;
  int sr = 0;                    // read slot; add slot = sr+1, clear = sr+2 (mod 3)
  for (int t = 0; t < TLEN; ++t) {
    const int sa = (sr + 1 < 3) ? sr + 1 : sr - 2;
    const int sc = (sr + 2 < 3) ? sr + 2 : sr - 1;
    if (tid == 0) hWb_sh[sc] = 0.0f;

    const float hWb = hWb_sh[sr];                    // broadcast read
    const half2_t x2 = x_sh2[t];                     // broadcast read
    const float beta = fast_sigmoid(dot2acc(x2, wbx2, hWb + bbeta));

    // momentum update (identical on all 4 lanes of a d-group)
    vr = beta * vr + sv * dot2acc(x2, wih_r, bih_r);
    vz = beta * vz + sv * dot2acc(x2, wih_z, bih_z);
    vn = beta * vn + sv * dot2acc(x2, wih_n, bih_n);

    // partial dots over this thread's 8 interleaved 16-B h-blocks
    float ar = 0.0f, az = 0.0f, an = 0.0f;
    const float4* hb4 = reinterpret_cast<const float4*>(hbuf[cur]);
#pragma unroll
    for (int i = 0; i < 8; ++i) {
      float4 f = hb4[4 * i + q];
      half2_t h0 = __builtin_bit_cast(half2_t, f.x);
      half2_t h1 = __builtin_bit_cast(half2_t, f.y);
      half2_t h2 = __builtin_bit_cast(half2_t, f.z);
      half2_t h3 = __builtin_bit_cast(half2_t, f.w);
      ar = dot2acc(wr[4 * i + 0], h0, ar);
      az = dot2acc(wz[4 * i + 0], h0, az);
      an = dot2acc(wn[4 * i + 0], h0, an);
      ar = dot2acc(wr[4 * i + 1], h1, ar);
      az = dot2acc(wz[4 * i + 1], h1, az);
      an = dot2acc(wn[4 * i + 1], h1, an);
      ar = dot2acc(wr[4 * i + 2], h2, ar);
      az = dot2acc(wz[4 * i + 2], h2, az);
      an = dot2acc(wn[4 * i + 2], h2, an);
      ar = dot2acc(wr[4 * i + 3], h3, ar);
      az = dot2acc(wz[4 * i + 3], h3, az);
      an = dot2acc(wn[4 * i + 3], h3, an);
    }
    // combine the 4 quarter-partials within the d-group (all lanes get sum)
    ar += __shfl_xor(ar, 1, 64);  az += __shfl_xor(az, 1, 64);  an += __shfl_xor(an, 1, 64);
    ar += __shfl_xor(ar, 2, 64);  az += __shfl_xor(az, 2, 64);  an += __shfl_xor(an, 2, 64);

    // gates (redundant on the 4 lanes of the group -> no divergence)
    const float r = fast_sigmoid(vr + ar + bhh_r);
    const float z = fast_sigmoid(vz + az + bhh_z);
    const float hn = an + bhh_n;
    const float n = fast_tanh(vn + r * hn);
    h_old = (1.0f - z) * n + z * h_old;

    const int nxt = cur ^ 1;
    if (q == 0) reinterpret_cast<_Float16*>(hbuf[nxt])[d] = (_Float16)h_old;

    // h_new . Wb_h -> rotating slot for next step's beta
    float p = (q == 0) ? h_old * wbh_t : 0.0f;
#pragma unroll
    for (int off = 32; off; off >>= 1) p += __shfl_xor(p, off, 64);
    if (lane == 0) atomicAdd(&hWb_sh[sa], p);
    if (tid == 0) betas[(size_t)b * TLEN + t] = beta;
    __syncthreads();
    cur = nxt;
    sr = sa;
  }

  // ---- head: out[b] = h_T . W_head + b_head ----
  float hp = (q == 0) ? h_old * W_head[d] : 0.0f;
#pragma unroll
  for (int off = 32; off; off >>= 1) hp += __shfl_xor(hp, off, 64);
  if (lane == 0) atomicAdd(&head_sh, hp);
  __syncthreads();
  if (tid == 0) out[b] = head_sh + b_head[0];
}

extern "C" void kernel_launch(void* const* d_in, const int* in_sizes, int n_in,
                              void* d_out, int out_size, void* d_ws, size_t ws_size,
                              hipStream_t stream) {
  const float* x      = (const float*)d_in[0];
  const float* W_ih   = (const float*)d_in[1];
  const float* W_hh   = (const float*)d_in[2];
  const float* b_ih   = (const float*)d_in[3];
  const float* b_hh   = (const float*)d_in[4];
  const float* Wb_x   = (const float*)d_in[5];
  const float* Wb_h   = (const float*)d_in[6];
  const float* b_beta = (const float*)d_in[7];
  const float* s      = (const float*)d_in[8];
  const float* W_head = (const float*)d_in[9];
  const float* b_head = (const float*)d_in[10];
  float* out = (float*)d_out;

  momgru_persistent<<<dim3(BATCH), dim3(1024), 0, stream>>>(
      x, W_ih, W_hh, b_ih, b_hh, Wb_x, Wb_h, b_beta, s, W_head, b_head, out);
}

// Round 5
// 1466.940 us; speedup vs baseline: 1.2664x; 1.2664x over previous
//
#include <hip/hip_runtime.h>

#define HID 256
#define TLEN 1024
#define BATCH 128

typedef _Float16 half2_t __attribute__((ext_vector_type(2)));

__device__ __forceinline__ float fexp2(float x) { return __builtin_amdgcn_exp2f(x); }
__device__ __forceinline__ float frcp(float x)  { return __builtin_amdgcn_rcpf(x); }
__device__ __forceinline__ float fast_sigmoid(float x) {
  return frcp(1.0f + fexp2(-1.442695040888963f * x));
}
__device__ __forceinline__ float fast_tanh(float x) {
  float e = fexp2(2.885390081777927f * x);
  return 1.0f - 2.0f * frcp(e + 1.0f);
}
__device__ __forceinline__ float dot2acc(half2_t a, half2_t b, float c) {
  return __builtin_amdgcn_fdot2(a, b, c, false);   // v_dot2_f32_f16
}
__device__ __forceinline__ unsigned pack2(float a, float b) {
  half2_t h{(_Float16)a, (_Float16)b};
  return __builtin_bit_cast(unsigned, h);
}
__device__ __forceinline__ half2_t uph(unsigned u) {
  return __builtin_bit_cast(half2_t, u);
}
__device__ __forceinline__ half2_t uphf(float f) {
  return __builtin_bit_cast(half2_t, f);
}

// ---- prep: repack n-gate (rows 512..767 of W_hh) to f16 in d_ws, laid out so
// main-kernel thread t's chunk j is the contiguous 16B at (j*512+t)*16.
// Thread t=(d<<1)|half owns k-elems [(2j+half)*8, +8) of row 512+d.
__global__ void pack_n_f16(const float* __restrict__ W_hh, uint4* __restrict__ ws) {
  const int m = blockIdx.x * 256 + threadIdx.x;   // [0, 8192)
  const int c = m >> 9, t = m & 511;
  const int d = t >> 1, half = t & 1;
  const float* row = W_hh + (size_t)(2 * HID + d) * HID + (2 * c + half) * 8;
  uint4 u;
  u.x = pack2(row[0], row[1]);
  u.y = pack2(row[2], row[3]);
  u.z = pack2(row[4], row[5]);
  u.w = pack2(row[6], row[7]);
  ws[m] = u;
}

// One block per batch element, 512 threads (8 waves, 2/SIMD; grant = 128 VGPRs,
// proven R2/R3). Thread (d=tid>>1, half=tid&1) owns k-blocks {2j+half} (16B f16
// blocks, j=0..15) of W_hh rows {d, 256+d, 512+d}:
//   r-gate: 16 blocks in regs (64 half2)      z-gate: j<10 regs (40), j>=10 LDS
//   n-gate: streamed from L2-resident f16 workspace copy each step (3-deep
//           manual prefetch pipeline; same bytes for every block -> L2 hits).
// Register weight demand 104 + temps ~= the 128 grant (small spill OK — the
// 150-dword spills of R1-R4 were the disaster, not a ~10-dword one).
__global__ __launch_bounds__(512, 1)
void momgru_persistent(const float* __restrict__ x,
                       const float* __restrict__ W_ih,
                       const float* __restrict__ W_hh,
                       const float* __restrict__ b_ih,
                       const float* __restrict__ b_hh,
                       const float* __restrict__ Wb_x,
                       const float* __restrict__ Wb_h,
                       const float* __restrict__ b_beta,
                       const float* __restrict__ s_ptr,
                       const float* __restrict__ W_head,
                       const float* __restrict__ b_head,
                       const uint4* __restrict__ nws,
                       float* __restrict__ out)  // [0,128) head, [128,128+B*T) betas
{
  const int b    = blockIdx.x;
  const int tid  = threadIdx.x;
  const int lane = tid & 63;
  const int wv   = tid >> 6;     // 0..7
  const int d    = tid >> 1;
  const int half = tid & 1;

  __shared__ half2_t x_sh2[TLEN];         // 4 KB  (x packed f16)
  __shared__ half2_t hbuf[2][HID / 2];    // 1 KB  (double-buffered f16 h)
  __shared__ float   red[2][8];           // 64 B  (per-wave partials)
  __shared__ uint4   zlds[6 * 512];       // 48 KB (z-gate blocks j=10..15)
  // total ~53.3 KB < 64 KB safe limit

  // ---- stage x as packed f16 ----
  const float* xb = x + (size_t)b * TLEN * 2;
  for (int i = tid; i < TLEN; i += 512) {
    float2 xv = reinterpret_cast<const float2*>(xb)[i];
    x_sh2[i] = half2_t{(_Float16)xv.x, (_Float16)xv.y};
  }

  // ---- r-gate (all 16 blocks) and z-gate (10 blocks) into registers ----
  half2_t wr[64], wz[40];
  {
    const float4* rowr = reinterpret_cast<const float4*>(W_hh + (size_t)(0 * HID + d) * HID);
#pragma unroll
    for (int j = 0; j < 16; ++j) {
      const int jb = 2 * j + half;
      float4 f0 = rowr[2 * jb], f1 = rowr[2 * jb + 1];
      wr[4 * j + 0] = half2_t{(_Float16)f0.x, (_Float16)f0.y};
      wr[4 * j + 1] = half2_t{(_Float16)f0.z, (_Float16)f0.w};
      wr[4 * j + 2] = half2_t{(_Float16)f1.x, (_Float16)f1.y};
      wr[4 * j + 3] = half2_t{(_Float16)f1.z, (_Float16)f1.w};
    }
  }
  {
    const float4* rowz = reinterpret_cast<const float4*>(W_hh + (size_t)(1 * HID + d) * HID);
#pragma unroll
    for (int j = 0; j < 10; ++j) {
      const int jb = 2 * j + half;
      float4 f0 = rowz[2 * jb], f1 = rowz[2 * jb + 1];
      wz[4 * j + 0] = half2_t{(_Float16)f0.x, (_Float16)f0.y};
      wz[4 * j + 1] = half2_t{(_Float16)f0.z, (_Float16)f0.w};
      wz[4 * j + 2] = half2_t{(_Float16)f1.x, (_Float16)f1.y};
      wz[4 * j + 3] = half2_t{(_Float16)f1.z, (_Float16)f1.w};
    }
    // z-gate blocks 10..15 -> LDS (thread-private slices; no barrier needed)
#pragma unroll
    for (int j = 10; j < 16; ++j) {
      const int jb = 2 * j + half;
      float4 f0 = rowz[2 * jb], f1 = rowz[2 * jb + 1];
      uint4 u;
      u.x = pack2(f0.x, f0.y);
      u.y = pack2(f0.z, f0.w);
      u.z = pack2(f1.x, f1.y);
      u.w = pack2(f1.z, f1.w);
      zlds[(j - 10) * 512 + tid] = u;
    }
  }

  // ---- per-thread constants ----
  const half2_t wih_r = half2_t{(_Float16)W_ih[2 * d],             (_Float16)W_ih[2 * d + 1]};
  const half2_t wih_z = half2_t{(_Float16)W_ih[2 * (HID + d)],     (_Float16)W_ih[2 * (HID + d) + 1]};
  const half2_t wih_n = half2_t{(_Float16)W_ih[2 * (2 * HID + d)], (_Float16)W_ih[2 * (2 * HID + d) + 1]};
  const float bih_r = b_ih[d], bih_z = b_ih[HID + d], bih_n = b_ih[2 * HID + d];
  const float bhh_r = b_hh[d], bhh_z = b_hh[HID + d], bhh_n = b_hh[2 * HID + d];
  const half2_t wbx2 = half2_t{(_Float16)Wb_x[0], (_Float16)Wb_x[1]};
  const float bbeta = b_beta[0], sv = s_ptr[0];
  const float wbh_t = Wb_h[d];

  // ---- init state ----
  if (tid < HID / 2) {
    hbuf[0][tid] = half2_t{(_Float16)0.0f, (_Float16)0.0f};
    hbuf[1][tid] = half2_t{(_Float16)0.0f, (_Float16)0.0f};
  }
  float h_old = 0.0f, vr = 0.0f, vz = 0.0f, vn = 0.0f;
  float hWb = 0.0f;
  float* betas = out + BATCH;
  const uint4* nrow = nws + tid;          // chunk j at nrow[j*512]
  __syncthreads();

  int cur = 0;
  for (int t = 0; t < TLEN; ++t) {
    const half2_t x2 = x_sh2[t];
    const float beta = fast_sigmoid(dot2acc(x2, wbx2, hWb + bbeta));

    vr = beta * vr + sv * dot2acc(x2, wih_r, bih_r);
    vz = beta * vz + sv * dot2acc(x2, wih_z, bih_z);
    vn = beta * vn + sv * dot2acc(x2, wih_n, bih_n);

    float ar = 0.0f, az = 0.0f, an = 0.0f;
    const float4* hb4 = reinterpret_cast<const float4*>(hbuf[cur]);

    uint4 nb[3];
    nb[0] = nrow[0 * 512];
    nb[1] = nrow[1 * 512];
    nb[2] = nrow[2 * 512];
#pragma unroll
    for (int j = 0; j < 16; ++j) {
      float4 hf = hb4[2 * j + half];                 // broadcast-pair ds_read_b128
      const uint4 nv = nb[j % 3];
      if (j + 3 < 16) nb[j % 3] = nrow[(j + 3) * 512];   // prefetch depth 3
      half2_t h0 = uphf(hf.x), h1 = uphf(hf.y), h2 = uphf(hf.z), h3 = uphf(hf.w);

      ar = dot2acc(wr[4 * j + 0], h0, ar);
      an = dot2acc(uph(nv.x), h0, an);
      ar = dot2acc(wr[4 * j + 1], h1, ar);
      an = dot2acc(uph(nv.y), h1, an);
      ar = dot2acc(wr[4 * j + 2], h2, ar);
      an = dot2acc(uph(nv.z), h2, an);
      ar = dot2acc(wr[4 * j + 3], h3, ar);
      an = dot2acc(uph(nv.w), h3, an);

      if (j < 10) {
        az = dot2acc(wz[4 * j + 0], h0, az);
        az = dot2acc(wz[4 * j + 1], h1, az);
        az = dot2acc(wz[4 * j + 2], h2, az);
        az = dot2acc(wz[4 * j + 3], h3, az);
      } else {
        const uint4 zv = zlds[(j - 10) * 512 + tid];
        az = dot2acc(uph(zv.x), h0, az);
        az = dot2acc(uph(zv.y), h1, az);
        az = dot2acc(uph(zv.z), h2, az);
        az = dot2acc(uph(zv.w), h3, az);
      }
    }

    // combine (d,half) partials — both lanes of the pair get the full sums
    ar += __shfl_xor(ar, 1, 64);
    az += __shfl_xor(az, 1, 64);
    an += __shfl_xor(an, 1, 64);

    const float r = fast_sigmoid(vr + ar + bhh_r);
    const float z = fast_sigmoid(vz + az + bhh_z);
    const float n = fast_tanh(vn + r * (an + bhh_n));
    h_old = (1.0f - z) * n + z * h_old;

    const int nxt = cur ^ 1;
    if (half == 0) reinterpret_cast<_Float16*>(hbuf[nxt])[d] = (_Float16)h_old;

    float p = (half == 0) ? h_old * wbh_t : 0.0f;
#pragma unroll
    for (int off = 32; off; off >>= 1) p += __shfl_xor(p, off, 64);
    const int rb = t & 1;
    if (lane == 0) red[rb][wv] = p;
    if (tid == 0) betas[(size_t)b * TLEN + t] = beta;
    __syncthreads();
    hWb = red[rb][0] + red[rb][1] + red[rb][2] + red[rb][3] +
          red[rb][4] + red[rb][5] + red[rb][6] + red[rb][7];
    cur = nxt;
  }

  // ---- head ----
  float hp = (half == 0) ? h_old * W_head[d] : 0.0f;
#pragma unroll
  for (int off = 32; off; off >>= 1) hp += __shfl_xor(hp, off, 64);
  if (lane == 0) red[0][wv] = hp;
  __syncthreads();
  if (tid == 0) {
    out[b] = red[0][0] + red[0][1] + red[0][2] + red[0][3] +
             red[0][4] + red[0][5] + red[0][6] + red[0][7] + b_head[0];
  }
}

extern "C" void kernel_launch(void* const* d_in, const int* in_sizes, int n_in,
                              void* d_out, int out_size, void* d_ws, size_t ws_size,
                              hipStream_t stream) {
  const float* x      = (const float*)d_in[0];
  const float* W_ih   = (const float*)d_in[1];
  const float* W_hh   = (const float*)d_in[2];
  const float* b_ih   = (const float*)d_in[3];
  const float* b_hh   = (const float*)d_in[4];
  const float* Wb_x   = (const float*)d_in[5];
  const float* Wb_h   = (const float*)d_in[6];
  const float* b_beta = (const float*)d_in[7];
  const float* s      = (const float*)d_in[8];
  const float* W_head = (const float*)d_in[9];
  const float* b_head = (const float*)d_in[10];
  float* out = (float*)d_out;
  uint4* nws = (uint4*)d_ws;   // needs 8192*16 = 128 KB of workspace

  pack_n_f16<<<dim3(32), dim3(256), 0, stream>>>(W_hh, nws);
  momgru_persistent<<<dim3(BATCH), dim3(512), 0, stream>>>(
      x, W_ih, W_hh, b_ih, b_hh, Wb_x, Wb_h, b_beta, s, W_head, b_head,
      (const uint4*)nws, out);
}

// Round 6
// 1331.434 us; speedup vs baseline: 1.3953x; 1.1018x over previous
//
#include <hip/hip_runtime.h>

#define HID 256
#define TLEN 1024
#define BATCH 128

typedef _Float16 half2_t __attribute__((ext_vector_type(2)));

__device__ __forceinline__ float fexp2(float x) { return __builtin_amdgcn_exp2f(x); }
__device__ __forceinline__ float frcp(float x)  { return __builtin_amdgcn_rcpf(x); }
__device__ __forceinline__ float fast_sigmoid(float x) {
  return frcp(1.0f + fexp2(-1.442695040888963f * x));
}
__device__ __forceinline__ float fast_tanh(float x) {
  float e = fexp2(2.885390081777927f * x);
  return 1.0f - 2.0f * frcp(e + 1.0f);
}
__device__ __forceinline__ float dot2acc(half2_t a, half2_t b, float c) {
  return __builtin_amdgcn_fdot2(a, b, c, false);   // v_dot2_f32_f16
}
__device__ __forceinline__ unsigned pack2(float a, float b) {
  half2_t h{(_Float16)a, (_Float16)b};
  return __builtin_bit_cast(unsigned, h);
}
__device__ __forceinline__ half2_t uph(unsigned u) { return __builtin_bit_cast(half2_t, u); }
__device__ __forceinline__ half2_t uphf(float f)   { return __builtin_bit_cast(half2_t, f); }

// DPP cross-lane adds on the VALU pipe (replaces ds_swizzle-based __shfl_xor).
#define DPP_ADD(var, ctrl, rmask)                                              \
  var += __builtin_bit_cast(float, __builtin_amdgcn_update_dpp(                \
      0, __builtin_bit_cast(int, var), (ctrl), (rmask), 0xf, true))

// pair combine: quad_perm [1,0,3,2] -> both lanes of an even/odd pair get sum
#define DPP_PAIR_SUM(var) DPP_ADD(var, 0xB1, 0xf)

// full wave64 sum -> valid in lane 63 (canonical GCN row_shr/bcast chain)
__device__ __forceinline__ float wave_sum63(float p) {
  DPP_ADD(p, 0x111, 0xf);   // row_shr:1
  DPP_ADD(p, 0x112, 0xf);   // row_shr:2
  DPP_ADD(p, 0x114, 0xf);   // row_shr:4
  DPP_ADD(p, 0x118, 0xf);   // row_shr:8  -> lane15 of each row has row sum
  DPP_ADD(p, 0x142, 0xa);   // row_bcast:15 into rows 1,3
  DPP_ADD(p, 0x143, 0xc);   // row_bcast:31 into rows 2,3 -> lane63 total
  return p;
}

// LDS-only barrier: drain LDS (lgkmcnt) but leave global loads in flight
// (compiler's __syncthreads emits s_waitcnt vmcnt(0) which would stall on the
// n-stream prefetch ring issued just before the barrier).
#define LDS_BARRIER() asm volatile("s_waitcnt lgkmcnt(0)\n\ts_barrier" ::: "memory")

// ---- prep: repack n-gate (rows 512..767 of W_hh) to f16 in d_ws; main-kernel
// thread t's chunk j is the contiguous 16B at (j*512+t)*16.
__global__ void pack_n_f16(const float* __restrict__ W_hh, uint4* __restrict__ ws) {
  const int m = blockIdx.x * 256 + threadIdx.x;   // [0, 8192)
  const int c = m >> 9, t = m & 511;
  const int d = t >> 1, half = t & 1;
  const float* row = W_hh + (size_t)(2 * HID + d) * HID + (2 * c + half) * 8;
  uint4 u;
  u.x = pack2(row[0], row[1]);
  u.y = pack2(row[2], row[3]);
  u.z = pack2(row[4], row[5]);
  u.w = pack2(row[6], row[7]);
  ws[m] = u;
}

// One block per batch element, 512 threads (8 waves, 2/SIMD; 128-VGPR grant).
// Thread (d=tid>>1, half=tid&1) owns k-blocks {2j+half} of W_hh rows
// {d, 256+d, 512+d}: r-gate 16 blocks in regs, z-gate j<10 regs / j>=10 LDS,
// n-gate streamed from L2-resident f16 workspace (3-deep ring; next step's
// first 3 loads issued BEFORE the LDS-only barrier so they cross it in flight).
// All cross-lane combines/reductions are DPP (VALU) — zero DS shuffle traffic.
__global__ __launch_bounds__(512, 1)
void momgru_persistent(const float* __restrict__ x,
                       const float* __restrict__ W_ih,
                       const float* __restrict__ W_hh,
                       const float* __restrict__ b_ih,
                       const float* __restrict__ b_hh,
                       const float* __restrict__ Wb_x,
                       const float* __restrict__ Wb_h,
                       const float* __restrict__ b_beta,
                       const float* __restrict__ s_ptr,
                       const float* __restrict__ W_head,
                       const float* __restrict__ b_head,
                       const uint4* __restrict__ nws,
                       float* __restrict__ out)  // [0,128) head, [128,128+B*T) betas
{
  const int b    = blockIdx.x;
  const int tid  = threadIdx.x;
  const int lane = tid & 63;
  const int wv   = tid >> 6;     // 0..7
  const int d    = tid >> 1;
  const int half = tid & 1;

  __shared__ half2_t hbuf[2][HID / 2];    // 1 KB  double-buffered f16 h
  __shared__ float   red[2][8];           // 64 B  per-wave hWb partials
  __shared__ uint4   zlds[6 * 512];       // 48 KB z-gate blocks j=10..15

  // ---- r-gate (16 blocks) and z-gate (10 blocks) into registers ----
  half2_t wr[64], wz[40];
  {
    const float4* rowr = reinterpret_cast<const float4*>(W_hh + (size_t)(0 * HID + d) * HID);
#pragma unroll
    for (int j = 0; j < 16; ++j) {
      const int jb = 2 * j + half;
      float4 f0 = rowr[2 * jb], f1 = rowr[2 * jb + 1];
      wr[4 * j + 0] = half2_t{(_Float16)f0.x, (_Float16)f0.y};
      wr[4 * j + 1] = half2_t{(_Float16)f0.z, (_Float16)f0.w};
      wr[4 * j + 2] = half2_t{(_Float16)f1.x, (_Float16)f1.y};
      wr[4 * j + 3] = half2_t{(_Float16)f1.z, (_Float16)f1.w};
    }
  }
  {
    const float4* rowz = reinterpret_cast<const float4*>(W_hh + (size_t)(1 * HID + d) * HID);
#pragma unroll
    for (int j = 0; j < 10; ++j) {
      const int jb = 2 * j + half;
      float4 f0 = rowz[2 * jb], f1 = rowz[2 * jb + 1];
      wz[4 * j + 0] = half2_t{(_Float16)f0.x, (_Float16)f0.y};
      wz[4 * j + 1] = half2_t{(_Float16)f0.z, (_Float16)f0.w};
      wz[4 * j + 2] = half2_t{(_Float16)f1.x, (_Float16)f1.y};
      wz[4 * j + 3] = half2_t{(_Float16)f1.z, (_Float16)f1.w};
    }
#pragma unroll
    for (int j = 10; j < 16; ++j) {
      const int jb = 2 * j + half;
      float4 f0 = rowz[2 * jb], f1 = rowz[2 * jb + 1];
      uint4 u;
      u.x = pack2(f0.x, f0.y);
      u.y = pack2(f0.z, f0.w);
      u.z = pack2(f1.x, f1.y);
      u.w = pack2(f1.z, f1.w);
      zlds[(j - 10) * 512 + tid] = u;
    }
  }

  // ---- per-thread constants ----
  const half2_t wih_r = half2_t{(_Float16)W_ih[2 * d],             (_Float16)W_ih[2 * d + 1]};
  const half2_t wih_z = half2_t{(_Float16)W_ih[2 * (HID + d)],     (_Float16)W_ih[2 * (HID + d) + 1]};
  const half2_t wih_n = half2_t{(_Float16)W_ih[2 * (2 * HID + d)], (_Float16)W_ih[2 * (2 * HID + d) + 1]};
  const float bih_r = b_ih[d], bih_z = b_ih[HID + d], bih_n = b_ih[2 * HID + d];
  const float bhh_r = b_hh[d], bhh_z = b_hh[HID + d], bhh_n = b_hh[2 * HID + d];
  const half2_t wbx2 = half2_t{(_Float16)Wb_x[0], (_Float16)Wb_x[1]};
  const float bbeta = b_beta[0], sv = s_ptr[0];
  const float wbh_t = Wb_h[d];

  // ---- init state ----
  if (tid < HID / 2) {
    hbuf[0][tid] = half2_t{(_Float16)0.0f, (_Float16)0.0f};
    hbuf[1][tid] = half2_t{(_Float16)0.0f, (_Float16)0.0f};
  }
  float h_old = 0.0f, vr = 0.0f, vz = 0.0f, vn = 0.0f;
  float hWb = 0.0f;
  float* betas = out + BATCH;
  const uint4* nrow = nws + tid;                 // chunk j at nrow[j*512]
  const float2* xg2 = reinterpret_cast<const float2*>(x + (size_t)b * TLEN * 2);

  // preload n-ring and first x
  uint4 nb[3];
  nb[0] = nrow[0 * 512];
  nb[1] = nrow[1 * 512];
  nb[2] = nrow[2 * 512];
  float2 xv = xg2[0];
  __syncthreads();

  int cur = 0;
  for (int t = 0; t < TLEN; ++t) {
    const half2_t x2 = half2_t{(_Float16)xv.x, (_Float16)xv.y};
    xv = xg2[(t + 1 < TLEN) ? t + 1 : t];        // prefetch next x (1-step lead)

    const float beta = fast_sigmoid(dot2acc(x2, wbx2, hWb + bbeta));
    vr = beta * vr + sv * dot2acc(x2, wih_r, bih_r);
    vz = beta * vz + sv * dot2acc(x2, wih_z, bih_z);
    vn = beta * vn + sv * dot2acc(x2, wih_n, bih_n);

    float ar = 0.0f, az = 0.0f, an = 0.0f;
    const float4* hb4 = reinterpret_cast<const float4*>(hbuf[cur]);
#pragma unroll
    for (int j = 0; j < 16; ++j) {
      float4 hf = hb4[2 * j + half];             // broadcast-pair ds_read_b128
      const uint4 nv = nb[j % 3];
      if (j + 3 < 16) nb[j % 3] = nrow[(j + 3) * 512];
      half2_t h0 = uphf(hf.x), h1 = uphf(hf.y), h2 = uphf(hf.z), h3 = uphf(hf.w);

      ar = dot2acc(wr[4 * j + 0], h0, ar);
      an = dot2acc(uph(nv.x), h0, an);
      ar = dot2acc(wr[4 * j + 1], h1, ar);
      an = dot2acc(uph(nv.y), h1, an);
      ar = dot2acc(wr[4 * j + 2], h2, ar);
      an = dot2acc(uph(nv.z), h2, an);
      ar = dot2acc(wr[4 * j + 3], h3, ar);
      an = dot2acc(uph(nv.w), h3, an);

      if (j < 10) {
        az = dot2acc(wz[4 * j + 0], h0, az);
        az = dot2acc(wz[4 * j + 1], h1, az);
        az = dot2acc(wz[4 * j + 2], h2, az);
        az = dot2acc(wz[4 * j + 3], h3, az);
      } else {
        const uint4 zv = zlds[(j - 10) * 512 + tid];
        az = dot2acc(uph(zv.x), h0, az);
        az = dot2acc(uph(zv.y), h1, az);
        az = dot2acc(uph(zv.z), h2, az);
        az = dot2acc(uph(zv.w), h3, az);
      }
    }

    // pair combine on the VALU pipe (DPP), no DS
    DPP_PAIR_SUM(ar);
    DPP_PAIR_SUM(az);
    DPP_PAIR_SUM(an);

    const float r = fast_sigmoid(vr + ar + bhh_r);
    const float z = fast_sigmoid(vz + az + bhh_z);
    const float n = fast_tanh(vn + r * (an + bhh_n));
    h_old = (1.0f - z) * n + z * h_old;

    const int nxt = cur ^ 1;
    if (half == 0) reinterpret_cast<_Float16*>(hbuf[nxt])[d] = (_Float16)h_old;

    // hWb partial -> per-wave DPP sum -> one LDS write per wave
    float p = (half == 0) ? h_old * wbh_t : 0.0f;
    p = wave_sum63(p);
    const int rb = t & 1;
    if (lane == 63) red[rb][wv] = p;
    if (tid == 63) betas[(size_t)b * TLEN + t] = beta;

    // issue next step's ring head BEFORE the barrier (stays in flight:
    // LDS_BARRIER drains lgkmcnt only)
    nb[0] = nrow[0 * 512];
    nb[1] = nrow[1 * 512];
    nb[2] = nrow[2 * 512];

    LDS_BARRIER();
    hWb = red[rb][0] + red[rb][1] + red[rb][2] + red[rb][3] +
          red[rb][4] + red[rb][5] + red[rb][6] + red[rb][7];
    cur = nxt;
  }

  // ---- head: out[b] = h_T . W_head + b_head ----
  float hp = (half == 0) ? h_old * W_head[d] : 0.0f;
  hp = wave_sum63(hp);
  if (lane == 63) red[0][wv] = hp;
  __syncthreads();
  if (tid == 0) {
    out[b] = red[0][0] + red[0][1] + red[0][2] + red[0][3] +
             red[0][4] + red[0][5] + red[0][6] + red[0][7] + b_head[0];
  }
}

extern "C" void kernel_launch(void* const* d_in, const int* in_sizes, int n_in,
                              void* d_out, int out_size, void* d_ws, size_t ws_size,
                              hipStream_t stream) {
  const float* x      = (const float*)d_in[0];
  const float* W_ih   = (const float*)d_in[1];
  const float* W_hh   = (const float*)d_in[2];
  const float* b_ih   = (const float*)d_in[3];
  const float* b_hh   = (const float*)d_in[4];
  const float* Wb_x   = (const float*)d_in[5];
  const float* Wb_h   = (const float*)d_in[6];
  const float* b_beta = (const float*)d_in[7];
  const float* s      = (const float*)d_in[8];
  const float* W_head = (const float*)d_in[9];
  const float* b_head = (const float*)d_in[10];
  float* out = (float*)d_out;
  uint4* nws = (uint4*)d_ws;   // 8192*16 = 128 KB workspace

  pack_n_f16<<<dim3(32), dim3(256), 0, stream>>>(W_hh, nws);
  momgru_persistent<<<dim3(BATCH), dim3(512), 0, stream>>>(
      x, W_ih, W_hh, b_ih, b_hh, Wb_x, Wb_h, b_beta, s, W_head, b_head,
      (const uint4*)nws, out);
}

// Round 7
// 983.597 us; speedup vs baseline: 1.8888x; 1.3536x over previous
//
#include <hip/hip_runtime.h>

#define HID 256
#define TLEN 1024
#define BATCH 128

typedef _Float16 half2_t __attribute__((ext_vector_type(2)));

__device__ __forceinline__ float fexp2(float x) { return __builtin_amdgcn_exp2f(x); }
__device__ __forceinline__ float frcp(float x)  { return __builtin_amdgcn_rcpf(x); }
__device__ __forceinline__ float fast_sigmoid(float x) {
  return frcp(1.0f + fexp2(-1.442695040888963f * x));
}
__device__ __forceinline__ float fast_tanh(float x) {
  float e = fexp2(2.885390081777927f * x);
  return 1.0f - 2.0f * frcp(e + 1.0f);
}
__device__ __forceinline__ float dot2acc(half2_t a, half2_t b, float c) {
  return __builtin_amdgcn_fdot2(a, b, c, false);   // v_dot2_f32_f16
}

#if defined(__has_builtin) && __has_builtin(__builtin_amdgcn_sdot4)
#define SDOT4(a, b, c) __builtin_amdgcn_sdot4((int)(a), (int)(b), (c), false)
#else
__device__ __forceinline__ int SDOT4(int a, int b, int c) {
#pragma unroll
  for (int e = 0; e < 4; ++e)
    c += ((a << (24 - 8 * e)) >> 24) * ((b << (24 - 8 * e)) >> 24);
  return c;
}
#endif

// DPP helpers (VALU pipe; no DS traffic)
#define DPP_ADD_F(var, ctrl, rmask)                                            \
  var += __builtin_bit_cast(float, __builtin_amdgcn_update_dpp(                \
      0, __builtin_bit_cast(int, var), (ctrl), (rmask), 0xf, true))
#define DPP_PAIR_SUM_I(var)                                                    \
  var += __builtin_amdgcn_update_dpp(0, (var), 0xB1, 0xf, 0xf, true)
#define DPP_MOV_I(dst, src, ctrl)                                              \
  dst = __builtin_amdgcn_update_dpp(0, (src), (ctrl), 0xf, 0xf, true)

__device__ __forceinline__ float wave_sum63(float p) {
  DPP_ADD_F(p, 0x111, 0xf);   // row_shr:1
  DPP_ADD_F(p, 0x112, 0xf);   // row_shr:2
  DPP_ADD_F(p, 0x114, 0xf);   // row_shr:4
  DPP_ADD_F(p, 0x118, 0xf);   // row_shr:8
  DPP_ADD_F(p, 0x142, 0xa);   // row_bcast:15
  DPP_ADD_F(p, 0x143, 0xc);   // row_bcast:31 -> lane63 has total
  return p;
}

// LDS-only barrier (leave global loads in flight)
#define LDS_BARRIER() asm volatile("s_waitcnt lgkmcnt(0)\n\ts_barrier" ::: "memory")

// ---- prep: per-row symmetric i8 quantization of W_hh (768 rows x 256),
// packed so main-kernel thread t = 2d+(jb&1) gets k-block jb as one uint4 at
// wq[t*24 + g*8 + (jb>>1)]. scales[r] = amax_row/127.
__global__ void quant_whh(const float* __restrict__ W_hh, uint4* __restrict__ wq,
                          float* __restrict__ scales) {
  const int r = blockIdx.x * 256 + threadIdx.x;   // 0..767
  if (r >= 768) return;
  const float* row = W_hh + (size_t)r * HID;
  float amax = 0.0f;
  for (int k = 0; k < HID; ++k) amax = fmaxf(amax, fabsf(row[k]));
  amax = fmaxf(amax, 1e-20f);
  scales[r] = amax / 127.0f;
  const float inv = 127.0f / amax;
  const int g = r >> 8, d = r & 255;
  for (int jb = 0; jb < 16; ++jb) {
    unsigned w[4];
#pragma unroll
    for (int u = 0; u < 4; ++u) {
      unsigned bb = 0;
#pragma unroll
      for (int e = 0; e < 4; ++e) {
        int q = (int)rintf(row[jb * 16 + u * 4 + e] * inv);
        bb |= (unsigned)(q & 0xff) << (8 * e);
      }
      w[u] = bb;
    }
    wq[(size_t)(2 * d + (jb & 1)) * 24 + g * 8 + (jb >> 1)] = uint4{w[0], w[1], w[2], w[3]};
  }
}

// One block per batch element, 512 threads. Thread (d=tid>>1, half=tid&1) owns
// k-blocks {2i+half} (16 i8 each, i=0..7) of W_hh rows {d,256+d,512+d}, ALL
// register/LDS resident as i8 (r:8, z:8, n:4 blocks in regs = 80 VGPRs;
// n blocks i=4..7 in LDS 32 KB). No per-step global weight stream (R6 showed
// the f16 L2 n-stream ~2280 cyc/step was co-bottleneck with DS ~2100).
// h is quantized to i8 each step (f32 master copy stays in registers; only the
// matvec path sees i8) -> h-broadcast DS traffic halves to 64 KB/step/CU.
__global__ __launch_bounds__(512, 1)
void momgru_persistent(const float* __restrict__ x,
                       const float* __restrict__ W_ih,
                       const float* __restrict__ b_ih,
                       const float* __restrict__ b_hh,
                       const float* __restrict__ Wb_x,
                       const float* __restrict__ Wb_h,
                       const float* __restrict__ b_beta,
                       const float* __restrict__ s_ptr,
                       const float* __restrict__ W_head,
                       const float* __restrict__ b_head,
                       const uint4* __restrict__ wq,
                       const float* __restrict__ scales,
                       float* __restrict__ out)  // [0,128) head, [128,128+B*T) betas
{
  const int b    = blockIdx.x;
  const int tid  = threadIdx.x;
  const int lane = tid & 63;
  const int wv   = tid >> 6;
  const int d    = tid >> 1;
  const int half = tid & 1;

  __shared__ unsigned hbuf[2][HID / 4];   // 512 B: h as i8, double-buffered
  __shared__ float    red[2][8];          // per-wave hWb partials
  __shared__ uint4    nlds[4 * 512];      // 32 KB: n-gate blocks i=4..7

  // ---- load this thread's i8 weight slice ----
  const uint4* wqt = wq + (size_t)tid * 24;
  uint4 wr[8], wz[8], wn[4];
#pragma unroll
  for (int i = 0; i < 8; ++i) wr[i] = wqt[i];
#pragma unroll
  for (int i = 0; i < 8; ++i) wz[i] = wqt[8 + i];
#pragma unroll
  for (int i = 0; i < 4; ++i) wn[i] = wqt[16 + i];
#pragma unroll
  for (int i = 0; i < 4; ++i) nlds[i * 512 + tid] = wqt[20 + i];

  // ---- per-thread constants ----
  const half2_t wih_r = half2_t{(_Float16)W_ih[2 * d],             (_Float16)W_ih[2 * d + 1]};
  const half2_t wih_z = half2_t{(_Float16)W_ih[2 * (HID + d)],     (_Float16)W_ih[2 * (HID + d) + 1]};
  const half2_t wih_n = half2_t{(_Float16)W_ih[2 * (2 * HID + d)], (_Float16)W_ih[2 * (2 * HID + d) + 1]};
  const float bih_r = b_ih[d], bih_z = b_ih[HID + d], bih_n = b_ih[2 * HID + d];
  const float bhh_r = b_hh[d], bhh_z = b_hh[HID + d], bhh_n = b_hh[2 * HID + d];
  const float scr = scales[d] * (1.0f / 127.0f);
  const float scz = scales[HID + d] * (1.0f / 127.0f);
  const float scn = scales[2 * HID + d] * (1.0f / 127.0f);
  const half2_t wbx2 = half2_t{(_Float16)Wb_x[0], (_Float16)Wb_x[1]};
  const float bbeta = b_beta[0], sv = s_ptr[0];
  const float wbh_t = Wb_h[d];

  // ---- init state ----
  if (tid < HID / 4) { hbuf[0][tid] = 0u; hbuf[1][tid] = 0u; }
  float h_old = 0.0f, vr = 0.0f, vz = 0.0f, vn = 0.0f;
  float hWb = 0.0f;
  float* betas = out + BATCH;
  const float2* xg2 = reinterpret_cast<const float2*>(x + (size_t)b * TLEN * 2);
  float2 xv = xg2[0];
  __syncthreads();

  int cur = 0;
  for (int t = 0; t < TLEN; ++t) {
    const half2_t x2 = half2_t{(_Float16)xv.x, (_Float16)xv.y};
    xv = xg2[(t + 1 < TLEN) ? t + 1 : t];

    const float beta = fast_sigmoid(dot2acc(x2, wbx2, hWb + bbeta));
    vr = beta * vr + sv * dot2acc(x2, wih_r, bih_r);
    vz = beta * vz + sv * dot2acc(x2, wih_z, bih_z);
    vn = beta * vn + sv * dot2acc(x2, wih_n, bih_n);

    // i8 matvec over this thread's 8 interleaved 16-byte h-blocks
    int ar = 0, az = 0, an = 0;
    const int4* hb = reinterpret_cast<const int4*>(hbuf[cur]);
#pragma unroll
    for (int i = 0; i < 8; ++i) {
      const int4 hv = hb[2 * i + half];
      const uint4 wnv = (i < 4) ? *(const uint4*)&wn[i] : nlds[(i - 4) * 512 + tid];
      ar = SDOT4(hv.x, wr[i].x, ar);
      az = SDOT4(hv.x, wz[i].x, az);
      an = SDOT4(hv.x, wnv.x, an);
      ar = SDOT4(hv.y, wr[i].y, ar);
      az = SDOT4(hv.y, wz[i].y, az);
      an = SDOT4(hv.y, wnv.y, an);
      ar = SDOT4(hv.z, wr[i].z, ar);
      az = SDOT4(hv.z, wz[i].z, az);
      an = SDOT4(hv.z, wnv.z, an);
      ar = SDOT4(hv.w, wr[i].w, ar);
      az = SDOT4(hv.w, wz[i].w, az);
      an = SDOT4(hv.w, wnv.w, an);
    }
    DPP_PAIR_SUM_I(ar);
    DPP_PAIR_SUM_I(az);
    DPP_PAIR_SUM_I(an);

    const float r = fast_sigmoid(vr + (float)ar * scr + bhh_r);
    const float z = fast_sigmoid(vz + (float)az * scz + bhh_z);
    const float n = fast_tanh(vn + r * ((float)an * scn + bhh_n));
    h_old = (1.0f - z) * n + z * h_old;

    // quantize h -> i8, pack 4 bytes per writer lane (lane%8==0) via DPP
    const int nxt = cur ^ 1;
    int q = ((int)rintf(h_old * 127.0f)) & 0xff;
    int q1, q2, q3;
    DPP_MOV_I(q1, q, 0x102);   // row_shl:2 -> lane i gets lane i+2
    DPP_MOV_I(q2, q, 0x104);
    DPP_MOV_I(q3, q, 0x106);
    if ((lane & 7) == 0)
      hbuf[nxt][tid >> 3] = (unsigned)(q | (q1 << 8) | (q2 << 16) | (q3 << 24));

    // hWb partial -> per-wave DPP sum -> one LDS write per wave
    float p = (half == 0) ? h_old * wbh_t : 0.0f;
    p = wave_sum63(p);
    const int rb = t & 1;
    if (lane == 63) red[rb][wv] = p;
    if (tid == 63) betas[(size_t)b * TLEN + t] = beta;

    LDS_BARRIER();
    hWb = red[rb][0] + red[rb][1] + red[rb][2] + red[rb][3] +
          red[rb][4] + red[rb][5] + red[rb][6] + red[rb][7];
    cur = nxt;
  }

  // ---- head ----
  float hp = (half == 0) ? h_old * W_head[d] : 0.0f;
  hp = wave_sum63(hp);
  if (lane == 63) red[0][wv] = hp;
  __syncthreads();
  if (tid == 0) {
    out[b] = red[0][0] + red[0][1] + red[0][2] + red[0][3] +
             red[0][4] + red[0][5] + red[0][6] + red[0][7] + b_head[0];
  }
}

extern "C" void kernel_launch(void* const* d_in, const int* in_sizes, int n_in,
                              void* d_out, int out_size, void* d_ws, size_t ws_size,
                              hipStream_t stream) {
  const float* x      = (const float*)d_in[0];
  const float* W_ih   = (const float*)d_in[1];
  const float* W_hh   = (const float*)d_in[2];
  const float* b_ih   = (const float*)d_in[3];
  const float* b_hh   = (const float*)d_in[4];
  const float* Wb_x   = (const float*)d_in[5];
  const float* Wb_h   = (const float*)d_in[6];
  const float* b_beta = (const float*)d_in[7];
  const float* s      = (const float*)d_in[8];
  const float* W_head = (const float*)d_in[9];
  const float* b_head = (const float*)d_in[10];
  float* out = (float*)d_out;

  uint4* wq      = (uint4*)d_ws;                   // 512*24*16 = 192 KB
  float* scales  = (float*)((char*)d_ws + 512 * 24 * 16);   // +3 KB

  quant_whh<<<dim3(3), dim3(256), 0, stream>>>(W_hh, wq, scales);
  momgru_persistent<<<dim3(BATCH), dim3(512), 0, stream>>>(
      x, W_ih, b_ih, b_hh, Wb_x, Wb_h, b_beta, s, W_head, b_head,
      (const uint4*)wq, (const float*)scales, out);
}